// Round 3
// baseline (98.412 us; speedup 1.0000x reference)
//
#include <hip/hip_runtime.h>
#include <math.h>

// RESUS_NN_2327872274812: Q=8192, S=30, D=512.  FP32-exact, deterministic.
// r17 = r16 with the overlap actually realized. r16 post-mortem: q/w loads
// were issued BEFORE the first __syncthreads(); the compiler emits
// s_waitcnt vmcnt(0) before s_barrier, so the barrier drained the whole
// 16.8 MB query burst serially (same stall as r14's PIN4, different cause).
// Fix:
//  (A) q/w loads issued AFTER the stage-0 barrier, behind an
//      asm("":::"memory") anti-hoist fence; pass 0 is d-seg-outer so the
//      compiler's fine vmcnt(N) waits let compute consume segments as HBM
//      delivers them. No barrier between issue and last use.
//  (B) support chunks 1/2 prefetched into regs at the TOP of hot pass 0/1;
//      the post-hot barrier drain is then free (data needed right after),
//      and the ds_write scatter overlaps the 160-thread reduce phase.
// Accumulation orders (d-ascending per (q,row), reduce d 0..15, epilogue
// tree) are r14-identical -> absmax 0.0 preserved.
// thread = (ql 0..15, dseg 0..15, shalf 0..1): query ql, 32-float d-slice,
// 5 support rows per pass (shalf picks which half of the 10-row chunk).

#define QN 8192
#define SN 30
#define DN 512
#define BLK 512
#define QT 16            // queries per block
#define SCHUNK 10        // support rows per pass
#define NPASS 3
#define SROW 580         // floats per LDS support row (16 segs * 36 + 4)
#define PRW 17           // praw ql-dim stride (floats)
#define PSTR 31          // final part row stride (float2)

__global__ __launch_bounds__(BLK, 2)
void resus_one(const float* __restrict__ query,      // [Q][D]
               const float* __restrict__ support,    // [S][D]
               const float* __restrict__ support_y,  // [S]
               const float* __restrict__ support_pr, // [S]
               const float* __restrict__ query_pr,   // [Q]
               const float* __restrict__ fc1_w,      // [D]
               const float* __restrict__ adj_scale,  // [30]
               const float* __restrict__ adj_bias,   // [30]
               const int*   __restrict__ num_samples,// [1]
               float* __restrict__ out)              // [2*Q]
{
    __shared__ float  sp[SCHUNK * SROW];          // 23,200 B
    __shared__ float  praw_sc[SCHUNK * QT * PRW]; // 10,880 B
    __shared__ float  praw_sq[SCHUNK * QT * PRW]; // 10,880 B
    __shared__ float2 part[QT * PSTR];            //  3,968 B  total 48,928 B

    const int tid   = threadIdx.x;
    const int ql    = tid & 15;               // query slot (lane-fast)
    const int dseg  = (tid >> 4) & 15;        // 32-float d-segment
    const int shalf = tid >> 8;               // 0/1: which 5 rows of a chunk
    const int q     = blockIdx.x * QT + ql;
    const bool has2 = (tid < 256);            // 1280 - 1024 float4s

    // scatter index helper: i-th float4 of a chunk -> segmented LDS slot
#define SCAT(V, I) { const int i_ = (I), row_ = i_ >> 7, c4_ = i_ & 127; \
    *reinterpret_cast<float4*>(sp + row_ * SROW + 36 * (c4_ >> 3) + 4 * (c4_ & 7)) = (V); }

    // ---- stage chunk 0 (only these loads outstanding at the barrier) ----
    {
        const float4* sg0 = reinterpret_cast<const float4*>(support);
        float4 g0 = sg0[tid];                 // SCHUNK*128 = 1280 float4s
        float4 g1 = sg0[tid + 512];
        float4 g2;
        if (has2) g2 = sg0[tid + 1024];
        SCAT(g0, tid)
        SCAT(g1, tid + 512)
        if (has2) SCAT(g2, tid + 1024)
    }
    __syncthreads();
    // anti-hoist fence: q/w loads must NOT migrate above the barrier, or
    // its vmcnt(0) drain serializes the whole query burst (r16's failure).
    asm volatile("" ::: "memory");

    // ---- q + w slices, per-segment interleaved issue order ----
    const float* qp = query + (size_t)q * DN + dseg * 32;
    const float* wp = fc1_w + dseg * 32;
    float4 a0 = *reinterpret_cast<const float4*>(qp +  0);
    float4 w0 = *reinterpret_cast<const float4*>(wp +  0);
    float4 a1 = *reinterpret_cast<const float4*>(qp +  4);
    float4 w1 = *reinterpret_cast<const float4*>(wp +  4);
    float4 a2 = *reinterpret_cast<const float4*>(qp +  8);
    float4 w2 = *reinterpret_cast<const float4*>(wp +  8);
    float4 a3 = *reinterpret_cast<const float4*>(qp + 12);
    float4 w3 = *reinterpret_cast<const float4*>(wp + 12);
    float4 a4 = *reinterpret_cast<const float4*>(qp + 16);
    float4 w4 = *reinterpret_cast<const float4*>(wp + 16);
    float4 a5 = *reinterpret_cast<const float4*>(qp + 20);
    float4 w5 = *reinterpret_cast<const float4*>(wp + 20);
    float4 a6 = *reinterpret_cast<const float4*>(qp + 24);
    float4 w6 = *reinterpret_cast<const float4*>(wp + 24);
    float4 a7 = *reinterpret_cast<const float4*>(qp + 28);
    float4 w7 = *reinterpret_cast<const float4*>(wp + 28);

    // ---- prefetch chunk 1 into regs (consumed after the post-hot sync) ----
    const float4* sg1 = reinterpret_cast<const float4*>(support + (size_t)SCHUNK * DN);
    float4 h0 = sg1[tid];
    float4 h1 = sg1[tid + 512];
    float4 h2;
    if (has2) h2 = sg1[tid + 1024];

    // per-component chain: sub, fma(w,|d|,sc), fma(d,d,sq), d-ascending --
    // identical rounding to r14 for every (q, row).
#define ACCD(QV, WV, SV, SC, SQ) { float d_; \
    d_ = (QV).x - (SV).x; SC = fmaf((WV).x, fabsf(d_), SC); SQ = fmaf(d_, d_, SQ); \
    d_ = (QV).y - (SV).y; SC = fmaf((WV).y, fabsf(d_), SC); SQ = fmaf(d_, d_, SQ); \
    d_ = (QV).z - (SV).z; SC = fmaf((WV).z, fabsf(d_), SC); SQ = fmaf(d_, d_, SQ); \
    d_ = (QV).w - (SV).w; SC = fmaf((WV).w, fabsf(d_), SC); SQ = fmaf(d_, d_, SQ); }

    const int sbase = dseg * 36;
    const int pbase = ql * PRW + dseg;        // praw offset (sl adds QT*PRW)
    const int sl0   = shalf * (SCHUNK / 2);   // 0 or 5

    // ---- pass 0: d-seg-outer / row-inner; seg j waits only on a_j/w_j ----
    {
        const float* r0 = sp + (sl0 + 0) * SROW + sbase;
        const float* r1 = sp + (sl0 + 1) * SROW + sbase;
        const float* r2 = sp + (sl0 + 2) * SROW + sbase;
        const float* r3 = sp + (sl0 + 3) * SROW + sbase;
        const float* r4 = sp + (sl0 + 4) * SROW + sbase;
        float sc0 = 0.0f, sc1 = 0.0f, sc2 = 0.0f, sc3 = 0.0f, sc4 = 0.0f;
        float sq0 = 0.0f, sq1 = 0.0f, sq2 = 0.0f, sq3 = 0.0f, sq4 = 0.0f;

#define SEG0(AJ, WJ, OFF) { float4 s_; \
    s_ = *reinterpret_cast<const float4*>(r0 + (OFF)); ACCD(AJ, WJ, s_, sc0, sq0); \
    s_ = *reinterpret_cast<const float4*>(r1 + (OFF)); ACCD(AJ, WJ, s_, sc1, sq1); \
    s_ = *reinterpret_cast<const float4*>(r2 + (OFF)); ACCD(AJ, WJ, s_, sc2, sq2); \
    s_ = *reinterpret_cast<const float4*>(r3 + (OFF)); ACCD(AJ, WJ, s_, sc3, sq3); \
    s_ = *reinterpret_cast<const float4*>(r4 + (OFF)); ACCD(AJ, WJ, s_, sc4, sq4); }

        SEG0(a0, w0,  0) SEG0(a1, w1,  4) SEG0(a2, w2,  8) SEG0(a3, w3, 12)
        SEG0(a4, w4, 16) SEG0(a5, w5, 20) SEG0(a6, w6, 24) SEG0(a7, w7, 28)
#undef SEG0

        praw_sc[(sl0 + 0) * (QT * PRW) + pbase] = sc0;
        praw_sq[(sl0 + 0) * (QT * PRW) + pbase] = sq0;
        praw_sc[(sl0 + 1) * (QT * PRW) + pbase] = sc1;
        praw_sq[(sl0 + 1) * (QT * PRW) + pbase] = sq1;
        praw_sc[(sl0 + 2) * (QT * PRW) + pbase] = sc2;
        praw_sq[(sl0 + 2) * (QT * PRW) + pbase] = sq2;
        praw_sc[(sl0 + 3) * (QT * PRW) + pbase] = sc3;
        praw_sq[(sl0 + 3) * (QT * PRW) + pbase] = sq3;
        praw_sc[(sl0 + 4) * (QT * PRW) + pbase] = sc4;
        praw_sq[(sl0 + 4) * (QT * PRW) + pbase] = sq4;
    }

    // ---- pin q/w for passes 1-2 (r11-proven; after pass 0 so it never
    //      forces an early vmcnt drain) ----
#define PIN4(V) asm volatile("" : "+v"((V).x), "+v"((V).y), "+v"((V).z), "+v"((V).w))
    PIN4(a0); PIN4(a1); PIN4(a2); PIN4(a3);
    PIN4(a4); PIN4(a5); PIN4(a6); PIN4(a7);
    PIN4(w0); PIN4(w1); PIN4(w2); PIN4(w3);
    PIN4(w4); PIN4(w5); PIN4(w6); PIN4(w7);
#undef PIN4

    __syncthreads();   // praw visible; sp readers done; h-prefetch drained

    // ---- write chunk 1 into sp (overlaps reduce below) ----
    SCAT(h0, tid)
    SCAT(h1, tid + 512)
    if (has2) SCAT(h2, tid + 1024)

    // ---- pass-0 reduce over dseg: fixed ascending order ----
    if (tid < SCHUNK * QT) {           // 160 threads
        const int sl = tid >> 4, qq = tid & 15;
        const int b = sl * (QT * PRW) + qq * PRW;
        float sc = 0.0f, sq = 0.0f;
#pragma unroll
        for (int d = 0; d < 16; ++d) {
            sc += praw_sc[b + d];
            sq += praw_sq[b + d];
        }
        part[qq * PSTR + sl] = make_float2(sc, sq);
    }
    __syncthreads();   // chunk-1 visible; reduce0 done
    asm volatile("" ::: "memory");

    // ---- prefetch chunk 2 into regs (consumed after the post-hot sync) ----
    const float4* sg2 = reinterpret_cast<const float4*>(support + (size_t)2 * SCHUNK * DN);
    float4 k0 = sg2[tid];
    float4 k1 = sg2[tid + 512];
    float4 k2;
    if (has2) k2 = sg2[tid + 1024];

    // hot-loop macro (ambient sc/sq), r14-identical
#define ACC4(QV, WV, SV) { float d_; \
    d_ = (QV).x - (SV).x; sc = fmaf((WV).x, fabsf(d_), sc); sq = fmaf(d_, d_, sq); \
    d_ = (QV).y - (SV).y; sc = fmaf((WV).y, fabsf(d_), sc); sq = fmaf(d_, d_, sq); \
    d_ = (QV).z - (SV).z; sc = fmaf((WV).z, fabsf(d_), sc); sq = fmaf(d_, d_, sq); \
    d_ = (QV).w - (SV).w; sc = fmaf((WV).w, fabsf(d_), sc); sq = fmaf(d_, d_, sq); }

#define HOTPASS \
    _Pragma("unroll") \
    for (int k = 0; k < SCHUNK / 2; ++k) { \
        const int sl = sl0 + k; \
        const float* sr = sp + sl * SROW + sbase; \
        const float4 s0 = *reinterpret_cast<const float4*>(sr +  0); \
        const float4 s1 = *reinterpret_cast<const float4*>(sr +  4); \
        const float4 s2 = *reinterpret_cast<const float4*>(sr +  8); \
        const float4 s3 = *reinterpret_cast<const float4*>(sr + 12); \
        const float4 s4 = *reinterpret_cast<const float4*>(sr + 16); \
        const float4 s5 = *reinterpret_cast<const float4*>(sr + 20); \
        const float4 s6 = *reinterpret_cast<const float4*>(sr + 24); \
        const float4 s7 = *reinterpret_cast<const float4*>(sr + 28); \
        float sc = 0.0f, sq = 0.0f; \
        ACC4(a0, w0, s0) ACC4(a1, w1, s1) \
        ACC4(a2, w2, s2) ACC4(a3, w3, s3) \
        ACC4(a4, w4, s4) ACC4(a5, w5, s5) \
        ACC4(a6, w6, s6) ACC4(a7, w7, s7) \
        praw_sc[sl * (QT * PRW) + pbase] = sc; \
        praw_sq[sl * (QT * PRW) + pbase] = sq; \
    }

    // ---- pass 1 hot ----
    HOTPASS
    __syncthreads();   // praw visible; sp readers done; k-prefetch drained

    // ---- write chunk 2 into sp (overlaps reduce below) ----
    SCAT(k0, tid)
    SCAT(k1, tid + 512)
    if (has2) SCAT(k2, tid + 1024)

    // ---- pass-1 reduce ----
    if (tid < SCHUNK * QT) {
        const int sl = tid >> 4, qq = tid & 15;
        const int b = sl * (QT * PRW) + qq * PRW;
        float sc = 0.0f, sq = 0.0f;
#pragma unroll
        for (int d = 0; d < 16; ++d) {
            sc += praw_sc[b + d];
            sq += praw_sq[b + d];
        }
        part[qq * PSTR + SCHUNK + sl] = make_float2(sc, sq);
    }
    __syncthreads();   // chunk-2 visible; reduce1 done

    // ---- pass 2 hot ----
    HOTPASS
    __syncthreads();

    // ---- pass-2 reduce ----
    if (tid < SCHUNK * QT) {
        const int sl = tid >> 4, qq = tid & 15;
        const int b = sl * (QT * PRW) + qq * PRW;
        float sc = 0.0f, sq = 0.0f;
#pragma unroll
        for (int d = 0; d < 16; ++d) {
            sc += praw_sc[b + d];
            sq += praw_sq[b + d];
        }
        part[qq * PSTR + 2 * SCHUNK + sl] = make_float2(sc, sq);
    }
#undef HOTPASS
#undef ACC4
#undef ACCD
#undef SCAT
    __syncthreads();   // all part[] writes visible

    // ---- epilogue: 16 half-wave groups; group g = query g (r14) ----
    const int grp  = tid >> 5;                // 0..15
    const int s32  = tid & 31;
    const bool valid = (s32 < SN);
    const int  si  = valid ? s32 : 0;

    float dy = 0.0f;
    if (valid)
        dy = support_y[s32] - 1.0f / (1.0f + expf(-support_pr[s32]));

    const int ns = num_samples[0];
    const float ascale = fabsf(adj_scale[ns - 1]);
    const float abias  = adj_bias[ns - 1];

    const int qg = blockIdx.x * QT + grp;
    const float2 pr = part[grp * PSTR + si];

    float scv = valid ? pr.x : -1e30f;
    float ssv = valid ? pr.y : 0.0f;

    float m = scv;
#pragma unroll
    for (int off = 16; off >= 1; off >>= 1)
        m = fmaxf(m, __shfl_xor(m, off));

    float e   = valid ? expf(scv - m) : 0.0f;
    float den = e;
    float num = dy * e;
    float l2  = valid ? sqrtf(ssv) : 0.0f;
#pragma unroll
    for (int off = 16; off >= 1; off >>= 1) {
        den += __shfl_xor(den, off);
        num += __shfl_xor(num, off);
        l2  += __shfl_xor(l2,  off);
    }

    if (s32 == 0) {
        out[qg]      = num / den * ascale + abias + query_pr[qg];
        out[QN + qg] = l2 * (1.0f / (float)SN);
    }
}

extern "C" void kernel_launch(void* const* d_in, const int* in_sizes, int n_in,
                              void* d_out, int out_size, void* d_ws, size_t ws_size,
                              hipStream_t stream)
{
    const float* query      = (const float*)d_in[0];
    const float* support    = (const float*)d_in[1];
    const float* support_y  = (const float*)d_in[2];
    const float* support_pr = (const float*)d_in[3];
    const float* query_pr   = (const float*)d_in[4];
    const float* fc1_w      = (const float*)d_in[5];
    // d_in[6] = fc1_b: cancels in softmax, unused
    const float* adj_scale  = (const float*)d_in[7];
    const float* adj_bias   = (const float*)d_in[8];
    const int*   num_s      = (const int*)d_in[9];
    float* out = (float*)d_out;

    dim3 grid(QN / QT);      // 512 blocks x 8 waves = 4096 waves = 4/SIMD
    hipLaunchKernelGGL(resus_one, grid, dim3(BLK), 0, stream,
                       query, support, support_y, support_pr, query_pr,
                       fc1_w, adj_scale, adj_bias, num_s, out);
}

// Round 4
// 92.938 us; speedup vs baseline: 1.0589x; 1.0589x over previous
//
#include <hip/hip_runtime.h>
#include <math.h>

// RESUS_NN_2327872274812: Q=8192, S=30, D=512.  FP32-exact, deterministic.
// r18 = overlap fix (A) ONLY, isolated. History:
//   r14 93.3us (best) | r15 2q/thread 94.4 | r16 A-misplaced 94.0 |
//   r17 A-proper + reg-prefetch(B) 98.4 -- B blew the 128-VGPR cap from
//   __launch_bounds__(512,2) (64 a/w + 24 prefetch + 32 s-tile + 10 acc)
//   -> scratch spills. r18 drops B; passes 1-2 are r14 verbatim.
// Mechanism A: r14 serialized the 16.8 MB query burst (2.7us chip-wide)
// because PIN4/barriers forced s_waitcnt vmcnt(0) before any compute.
// Here: stage support chunk 0 (small, ~20KB L2-broadcast) -> barrier ->
// anti-hoist fence -> issue q/w interleaved -> pass 0 runs d-subseg-outer
// so float4 j of the q-slice is consumed while j+1.. are still in flight
// (compiler emits descending vmcnt(N) waits; no barrier until pass 0 ends).
// Accumulation orders (d-ascending per (q,row), reduce d 0..15, epilogue
// tree) are r14-identical -> absmax 0.0 preserved.
// thread = (ql 0..15, dseg 0..15, shalf 0..1): query ql, 32-float d-slice,
// 5 support rows per pass (shalf picks which half of the 10-row chunk).

#define QN 8192
#define SN 30
#define DN 512
#define BLK 512
#define QT 16            // queries per block
#define SCHUNK 10        // support rows per pass
#define NPASS 3
#define SROW 580         // floats per LDS support row (16 segs * 36 + 4)
#define PRW 17           // praw ql-dim stride (floats)
#define PSTR 31          // final part row stride (float2)

__global__ __launch_bounds__(BLK, 2)
void resus_one(const float* __restrict__ query,      // [Q][D]
               const float* __restrict__ support,    // [S][D]
               const float* __restrict__ support_y,  // [S]
               const float* __restrict__ support_pr, // [S]
               const float* __restrict__ query_pr,   // [Q]
               const float* __restrict__ fc1_w,      // [D]
               const float* __restrict__ adj_scale,  // [30]
               const float* __restrict__ adj_bias,   // [30]
               const int*   __restrict__ num_samples,// [1]
               float* __restrict__ out)              // [2*Q]
{
    __shared__ float  sp[SCHUNK * SROW];          // 23,200 B
    __shared__ float  praw_sc[SCHUNK * QT * PRW]; // 10,880 B
    __shared__ float  praw_sq[SCHUNK * QT * PRW]; // 10,880 B
    __shared__ float2 part[QT * PSTR];            //  3,968 B  total 48,928 B

    const int tid   = threadIdx.x;
    const int ql    = tid & 15;               // query slot (lane-fast)
    const int dseg  = (tid >> 4) & 15;        // 32-float d-segment
    const int shalf = tid >> 8;               // 0/1: which 5 rows of a chunk
    const int q     = blockIdx.x * QT + ql;
    const bool has2 = (tid < 256);            // 1280 - 1024 float4s

    // scatter index helper: i-th float4 of a chunk -> segmented LDS slot
#define SCAT(V, I) { const int i_ = (I), row_ = i_ >> 7, c4_ = i_ & 127; \
    *reinterpret_cast<float4*>(sp + row_ * SROW + 36 * (c4_ >> 3) + 4 * (c4_ & 7)) = (V); }

    // ---- stage chunk 0 (only these loads outstanding at the barrier) ----
    {
        const float4* sg0 = reinterpret_cast<const float4*>(support);
        float4 g0 = sg0[tid];                 // SCHUNK*128 = 1280 float4s
        float4 g1 = sg0[tid + 512];
        float4 g2;
        if (has2) g2 = sg0[tid + 1024];
        SCAT(g0, tid)
        SCAT(g1, tid + 512)
        if (has2) SCAT(g2, tid + 1024)
    }
    __syncthreads();
    // anti-hoist fence: q/w loads must NOT migrate above the barrier, or
    // its vmcnt(0) drain serializes the whole query burst (r16's failure).
    asm volatile("" ::: "memory");

    // ---- q + w slices, per-subsegment interleaved issue order ----
    const float* qp = query + (size_t)q * DN + dseg * 32;
    const float* wp = fc1_w + dseg * 32;
    float4 a0 = *reinterpret_cast<const float4*>(qp +  0);
    float4 w0 = *reinterpret_cast<const float4*>(wp +  0);
    float4 a1 = *reinterpret_cast<const float4*>(qp +  4);
    float4 w1 = *reinterpret_cast<const float4*>(wp +  4);
    float4 a2 = *reinterpret_cast<const float4*>(qp +  8);
    float4 w2 = *reinterpret_cast<const float4*>(wp +  8);
    float4 a3 = *reinterpret_cast<const float4*>(qp + 12);
    float4 w3 = *reinterpret_cast<const float4*>(wp + 12);
    float4 a4 = *reinterpret_cast<const float4*>(qp + 16);
    float4 w4 = *reinterpret_cast<const float4*>(wp + 16);
    float4 a5 = *reinterpret_cast<const float4*>(qp + 20);
    float4 w5 = *reinterpret_cast<const float4*>(wp + 20);
    float4 a6 = *reinterpret_cast<const float4*>(qp + 24);
    float4 w6 = *reinterpret_cast<const float4*>(wp + 24);
    float4 a7 = *reinterpret_cast<const float4*>(qp + 28);
    float4 w7 = *reinterpret_cast<const float4*>(wp + 28);

    // per-component chain: sub, fma(w,|d|,sc), fma(d,d,sq), d-ascending --
    // identical rounding to r14 for every (q, row).
#define ACCD(QV, WV, SV, SC, SQ) { float d_; \
    d_ = (QV).x - (SV).x; SC = fmaf((WV).x, fabsf(d_), SC); SQ = fmaf(d_, d_, SQ); \
    d_ = (QV).y - (SV).y; SC = fmaf((WV).y, fabsf(d_), SC); SQ = fmaf(d_, d_, SQ); \
    d_ = (QV).z - (SV).z; SC = fmaf((WV).z, fabsf(d_), SC); SQ = fmaf(d_, d_, SQ); \
    d_ = (QV).w - (SV).w; SC = fmaf((WV).w, fabsf(d_), SC); SQ = fmaf(d_, d_, SQ); }

    const int sbase = dseg * 36;
    const int pbase = ql * PRW + dseg;        // praw offset (sl adds QT*PRW)
    const int sl0   = shalf * (SCHUNK / 2);   // 0 or 5

    // ---- pass 0: subseg-outer / row-inner; step j waits only a_j/w_j ----
    {
        const float* r0 = sp + (sl0 + 0) * SROW + sbase;
        const float* r1 = sp + (sl0 + 1) * SROW + sbase;
        const float* r2 = sp + (sl0 + 2) * SROW + sbase;
        const float* r3 = sp + (sl0 + 3) * SROW + sbase;
        const float* r4 = sp + (sl0 + 4) * SROW + sbase;
        float sc0 = 0.0f, sc1 = 0.0f, sc2 = 0.0f, sc3 = 0.0f, sc4 = 0.0f;
        float sq0 = 0.0f, sq1 = 0.0f, sq2 = 0.0f, sq3 = 0.0f, sq4 = 0.0f;

#define SEG0(AJ, WJ, OFF) { float4 s_; \
    s_ = *reinterpret_cast<const float4*>(r0 + (OFF)); ACCD(AJ, WJ, s_, sc0, sq0); \
    s_ = *reinterpret_cast<const float4*>(r1 + (OFF)); ACCD(AJ, WJ, s_, sc1, sq1); \
    s_ = *reinterpret_cast<const float4*>(r2 + (OFF)); ACCD(AJ, WJ, s_, sc2, sq2); \
    s_ = *reinterpret_cast<const float4*>(r3 + (OFF)); ACCD(AJ, WJ, s_, sc3, sq3); \
    s_ = *reinterpret_cast<const float4*>(r4 + (OFF)); ACCD(AJ, WJ, s_, sc4, sq4); }

        SEG0(a0, w0,  0) SEG0(a1, w1,  4) SEG0(a2, w2,  8) SEG0(a3, w3, 12)
        SEG0(a4, w4, 16) SEG0(a5, w5, 20) SEG0(a6, w6, 24) SEG0(a7, w7, 28)
#undef SEG0

        praw_sc[(sl0 + 0) * (QT * PRW) + pbase] = sc0;
        praw_sq[(sl0 + 0) * (QT * PRW) + pbase] = sq0;
        praw_sc[(sl0 + 1) * (QT * PRW) + pbase] = sc1;
        praw_sq[(sl0 + 1) * (QT * PRW) + pbase] = sq1;
        praw_sc[(sl0 + 2) * (QT * PRW) + pbase] = sc2;
        praw_sq[(sl0 + 2) * (QT * PRW) + pbase] = sq2;
        praw_sc[(sl0 + 3) * (QT * PRW) + pbase] = sc3;
        praw_sq[(sl0 + 3) * (QT * PRW) + pbase] = sq3;
        praw_sc[(sl0 + 4) * (QT * PRW) + pbase] = sc4;
        praw_sq[(sl0 + 4) * (QT * PRW) + pbase] = sq4;
    }

    // ---- pin q/w for passes 1-2 (r11-proven; after pass 0 so it never
    //      forces an early vmcnt drain) ----
#define PIN4(V) asm volatile("" : "+v"((V).x), "+v"((V).y), "+v"((V).z), "+v"((V).w))
    PIN4(a0); PIN4(a1); PIN4(a2); PIN4(a3);
    PIN4(a4); PIN4(a5); PIN4(a6); PIN4(a7);
    PIN4(w0); PIN4(w1); PIN4(w2); PIN4(w3);
    PIN4(w4); PIN4(w5); PIN4(w6); PIN4(w7);
#undef PIN4

    __syncthreads();   // praw writes visible; sp readers done

    // ---- pass-0 reduce over dseg: fixed ascending order ----
    if (tid < SCHUNK * QT) {           // 160 threads
        const int sl = tid >> 4, qq = tid & 15;
        const int b = sl * (QT * PRW) + qq * PRW;
        float sc = 0.0f, sq = 0.0f;
#pragma unroll
        for (int d = 0; d < 16; ++d) {
            sc += praw_sc[b + d];
            sq += praw_sq[b + d];
        }
        part[qq * PSTR + sl] = make_float2(sc, sq);
    }

    // hot-loop macro (ambient sc/sq), r14-identical
#define ACC4(QV, WV, SV) { float d_; \
    d_ = (QV).x - (SV).x; sc = fmaf((WV).x, fabsf(d_), sc); sq = fmaf(d_, d_, sq); \
    d_ = (QV).y - (SV).y; sc = fmaf((WV).y, fabsf(d_), sc); sq = fmaf(d_, d_, sq); \
    d_ = (QV).z - (SV).z; sc = fmaf((WV).z, fabsf(d_), sc); sq = fmaf(d_, d_, sq); \
    d_ = (QV).w - (SV).w; sc = fmaf((WV).w, fabsf(d_), sc); sq = fmaf(d_, d_, sq); }

    // ---- passes 1-2: r14 verbatim (in-loop staging, row-outer hot) ----
    for (int pass = 1; pass < NPASS; ++pass) {
        __syncthreads();   // prev pass: sp reads + reduce complete

        const float4* sg = reinterpret_cast<const float4*>(
            support + (size_t)pass * SCHUNK * DN);
        for (int i = tid; i < SCHUNK * 128; i += BLK) {
            const int row = i >> 7, c4 = i & 127;
            *reinterpret_cast<float4*>(
                sp + row * SROW + 36 * (c4 >> 3) + 4 * (c4 & 7)) = sg[i];
        }
        __syncthreads();

#pragma unroll
        for (int k = 0; k < SCHUNK / 2; ++k) {
            const int sl = sl0 + k;
            const float* sr = sp + sl * SROW + sbase;
            const float4 s0 = *reinterpret_cast<const float4*>(sr +  0);
            const float4 s1 = *reinterpret_cast<const float4*>(sr +  4);
            const float4 s2 = *reinterpret_cast<const float4*>(sr +  8);
            const float4 s3 = *reinterpret_cast<const float4*>(sr + 12);
            const float4 s4 = *reinterpret_cast<const float4*>(sr + 16);
            const float4 s5 = *reinterpret_cast<const float4*>(sr + 20);
            const float4 s6 = *reinterpret_cast<const float4*>(sr + 24);
            const float4 s7 = *reinterpret_cast<const float4*>(sr + 28);

            float sc = 0.0f, sq = 0.0f;
            ACC4(a0, w0, s0) ACC4(a1, w1, s1)
            ACC4(a2, w2, s2) ACC4(a3, w3, s3)
            ACC4(a4, w4, s4) ACC4(a5, w5, s5)
            ACC4(a6, w6, s6) ACC4(a7, w7, s7)

            praw_sc[sl * (QT * PRW) + pbase] = sc;
            praw_sq[sl * (QT * PRW) + pbase] = sq;
        }
        __syncthreads();

        if (tid < SCHUNK * QT) {           // 160 threads
            const int sl = tid >> 4, qq = tid & 15;
            const int b = sl * (QT * PRW) + qq * PRW;
            float sc = 0.0f, sq = 0.0f;
#pragma unroll
            for (int d = 0; d < 16; ++d) {
                sc += praw_sc[b + d];
                sq += praw_sq[b + d];
            }
            part[qq * PSTR + pass * SCHUNK + sl] = make_float2(sc, sq);
        }
    }
#undef ACC4
#undef ACCD
#undef SCAT
    __syncthreads();   // all part[] writes visible

    // ---- epilogue: 16 half-wave groups; group g = query g (r14) ----
    const int grp  = tid >> 5;                // 0..15
    const int s32  = tid & 31;
    const bool valid = (s32 < SN);
    const int  si  = valid ? s32 : 0;

    float dy = 0.0f;
    if (valid)
        dy = support_y[s32] - 1.0f / (1.0f + expf(-support_pr[s32]));

    const int ns = num_samples[0];
    const float ascale = fabsf(adj_scale[ns - 1]);
    const float abias  = adj_bias[ns - 1];

    const int qg = blockIdx.x * QT + grp;
    const float2 pr = part[grp * PSTR + si];

    float scv = valid ? pr.x : -1e30f;
    float ssv = valid ? pr.y : 0.0f;

    float m = scv;
#pragma unroll
    for (int off = 16; off >= 1; off >>= 1)
        m = fmaxf(m, __shfl_xor(m, off));

    float e   = valid ? expf(scv - m) : 0.0f;
    float den = e;
    float num = dy * e;
    float l2  = valid ? sqrtf(ssv) : 0.0f;
#pragma unroll
    for (int off = 16; off >= 1; off >>= 1) {
        den += __shfl_xor(den, off);
        num += __shfl_xor(num, off);
        l2  += __shfl_xor(l2,  off);
    }

    if (s32 == 0) {
        out[qg]      = num / den * ascale + abias + query_pr[qg];
        out[QN + qg] = l2 * (1.0f / (float)SN);
    }
}

extern "C" void kernel_launch(void* const* d_in, const int* in_sizes, int n_in,
                              void* d_out, int out_size, void* d_ws, size_t ws_size,
                              hipStream_t stream)
{
    const float* query      = (const float*)d_in[0];
    const float* support    = (const float*)d_in[1];
    const float* support_y  = (const float*)d_in[2];
    const float* support_pr = (const float*)d_in[3];
    const float* query_pr   = (const float*)d_in[4];
    const float* fc1_w      = (const float*)d_in[5];
    // d_in[6] = fc1_b: cancels in softmax, unused
    const float* adj_scale  = (const float*)d_in[7];
    const float* adj_bias   = (const float*)d_in[8];
    const int*   num_s      = (const int*)d_in[9];
    float* out = (float*)d_out;

    dim3 grid(QN / QT);      // 512 blocks x 8 waves = 4096 waves = 4/SIMD
    hipLaunchKernelGGL(resus_one, grid, dim3(BLK), 0, stream,
                       query, support, support_y, support_pr, query_pr,
                       fc1_w, adj_scale, adj_bias, num_s, out);
}